// Round 1
// baseline (260.798 us; speedup 1.0000x reference)
//
#include <hip/hip_runtime.h>

#define HI 1440
#define WI 1920
#define NPIX (HI*WI)
#define EPSF 1e-8f

// ---------------- small 3x3 helpers (K0 only) ----------------
__device__ __forceinline__ void mat3mul(const float* A, const float* B, float* C) {
#pragma unroll
  for (int i = 0; i < 3; ++i)
#pragma unroll
    for (int j = 0; j < 3; ++j)
      C[i*3+j] = A[i*3+0]*B[0+j] + A[i*3+1]*B[3+j] + A[i*3+2]*B[6+j];
}

__device__ void rodrigues_dev(const float* v, float* R) {
  float th = sqrtf(v[0]*v[0] + v[1]*v[1] + v[2]*v[2]) + 1e-12f;
  float kx = v[0]/th, ky = v[1]/th, kz = v[2]/th;
  float st = sinf(th), ct = cosf(th);
  float S[9] = {0.f,-kz,ky, kz,0.f,-kx, -ky,kx,0.f};
  float S2[9];
  mat3mul(S, S, S2);
#pragma unroll
  for (int i = 0; i < 9; ++i) R[i] = st*S[i] + (1.f-ct)*S2[i];
  R[0] += 1.f; R[4] += 1.f; R[8] += 1.f;
}

// K0: compute per-target B = K*Rt*R1^T*Kinv (3x3) and a = K*Rt*(C1-Ct) (3)
__global__ void k_init(const float* __restrict__ focal, const float* __restrict__ aa,
                       const float* __restrict__ cen, float* __restrict__ mats) {
  if (threadIdx.x != 0 || blockIdx.x != 0) return;
  float f = focal[0];
  const float u0 = WI*0.5f - 0.5f;   // 959.5
  const float v0 = HI*0.5f - 0.5f;   // 719.5
  float K[9]  = {f,0.f,u0, 0.f,f,v0, 0.f,0.f,1.f};
  float Ki[9] = {1.f/f,0.f,-u0/f, 0.f,1.f/f,-v0/f, 0.f,0.f,1.f};
  float R1[9]; rodrigues_dev(aa, R1);
  float R1T[9];
  for (int i = 0; i < 3; ++i)
    for (int j = 0; j < 3; ++j) R1T[i*3+j] = R1[j*3+i];
  for (int t = 0; t < 2; ++t) {
    float Rt[9]; rodrigues_dev(aa + 3*(t+1), Rt);
    float A[9]; mat3mul(K, Rt, A);       // A = K*Rt
    float T[9]; mat3mul(A, R1T, T);
    float B[9]; mat3mul(T, Ki, B);       // B = A*R1^T*Kinv
    float Cd[3] = {cen[0]-cen[3*(t+1)+0], cen[1]-cen[3*(t+1)+1], cen[2]-cen[3*(t+1)+2]};
    float a0 = A[0]*Cd[0]+A[1]*Cd[1]+A[2]*Cd[2];
    float a1 = A[3]*Cd[0]+A[4]*Cd[1]+A[5]*Cd[2];
    float a2 = A[6]*Cd[0]+A[7]*Cd[1]+A[8]*Cd[2];
    float* M = mats + t*12;
    for (int i = 0; i < 9; ++i) M[i] = B[i];
    M[9] = a0; M[10] = a1; M[11] = a2;
  }
  mats[24] = f;
}

// grid_sample(align_corners=True, zeros): px,py in raw pixel coords
__device__ __forceinline__ float bilerp(const float* __restrict__ img, float px, float py) {
  float x0 = floorf(px), y0 = floorf(py);
  float wx = px - x0, wy = py - y0;
  float x1 = x0 + 1.f, y1 = y0 + 1.f;
  const float xmax = (float)(WI-1), ymax = (float)(HI-1);
  bool bx0 = (x0 >= 0.f) && (x0 <= xmax);
  bool bx1 = (x1 >= 0.f) && (x1 <= xmax);
  bool by0 = (y0 >= 0.f) && (y0 <= ymax);
  bool by1 = (y1 >= 0.f) && (y1 <= ymax);
  float v00 = 0.f, v10 = 0.f, v01 = 0.f, v11 = 0.f;
  if (bx0 && by0) v00 = img[(int)y0*WI + (int)x0];
  if (bx1 && by0) v10 = img[(int)y0*WI + (int)x1];
  if (bx0 && by1) v01 = img[(int)y1*WI + (int)x0];
  if (bx1 && by1) v11 = img[(int)y1*WI + (int)x1];
  return (1.f-wy)*((1.f-wx)*v00 + wx*v10) + wy*((1.f-wx)*v01 + wx*v11);
}

// K1: per-pixel homography warp + bilinear sample of both targets
__global__ __launch_bounds__(256) void k_warp(const float* __restrict__ depth,
                                              const float* __restrict__ tgts,
                                              const float* __restrict__ mats,
                                              float* __restrict__ warped) {
  int idx = blockIdx.x*256 + threadIdx.x;
  if (idx >= NPIX) return;
  int y = idx / WI, x = idx - y*WI;
  float d  = depth[idx];
  float dl = (x > 0)    ? depth[idx-1]  : 0.f;
  float dr = (x < WI-1) ? depth[idx+1]  : 0.f;
  float dt = (y > 0)    ? depth[idx-WI] : 0.f;
  float db = (y < HI-1) ? depth[idx+WI] : 0.f;
  float du = 0.5f*(dr - dl);
  float dv = 0.5f*(db - dt);
  float f = mats[24];
  float fx = (float)x, fy = (float)y;
  float nx = f*du, ny = f*dv;
  float nz = (960.f - fx)*du + (720.f - fy)*dv - d;
  float nn = sqrtf(nx*nx + ny*ny + nz*nz) + EPSF;
  float wsc = 1.f/(nn*(d + EPSF));       // combines normalize + /(depth+eps)
  float px = (fx - 959.5f)/f, py = (fy - 719.5f)/f;  // Kinv*[x,y,1] (first two comps)
  float s = (nx*px + ny*py + nz)*wsc;    // n_d . (Kinv c)
#pragma unroll
  for (int t = 0; t < 2; ++t) {
    const float* M = mats + t*12;
    float w0 = M[0]*fx + M[1]*fy + M[2] + M[9]*s;
    float w1 = M[3]*fx + M[4]*fy + M[5] + M[10]*s;
    float w2 = M[6]*fx + M[7]*fy + M[8] + M[11]*s;
    float sx = w0/(w2 + EPSF);
    float sy = w1/(w2 + EPSF);
    warped[t*NPIX + idx] = bilerp(tgts + t*NPIX, sx, sy);
  }
}

// K2: 7-tap horizontal box SUM (zero padded), z=0:ref z=1,2:warped
__global__ __launch_bounds__(256) void k_rowbox(const float* __restrict__ ref,
                                                const float* __restrict__ warped,
                                                float* __restrict__ tmp) {
  int idx = blockIdx.x*256 + threadIdx.x;
  int z = blockIdx.y;
  const float* src = (z == 0) ? ref : (warped + (size_t)(z-1)*NPIX);
  int y = idx / WI, x = idx - y*WI;
  float s = 0.f;
#pragma unroll
  for (int d = -3; d <= 3; ++d) {
    int xx = x + d;
    if (xx >= 0 && xx < WI) s += src[y*WI + xx];
  }
  tmp[(size_t)z*NPIX + idx] = s;
}

// K3: 7-tap vertical box sum of row sums, /49, subtract from center -> rc / tc
__global__ __launch_bounds__(256) void k_colbox_center(const float* __restrict__ ref,
                                                       const float* __restrict__ warped,
                                                       const float* __restrict__ tmp,
                                                       float* __restrict__ rc,
                                                       float* __restrict__ tc) {
  int idx = blockIdx.x*256 + threadIdx.x;
  int z = blockIdx.y;
  int y = idx / WI, x = idx - y*WI;
  const float* t = tmp + (size_t)z*NPIX;
  float s = 0.f;
#pragma unroll
  for (int d = -3; d <= 3; ++d) {
    int yy = y + d;
    if (yy >= 0 && yy < HI) s += t[yy*WI + x];
  }
  float mean = s * (1.f/49.f);
  float center = (z == 0) ? ref[idx] : warped[(size_t)(z-1)*NPIX + idx];
  float out = center - mean;
  if (z == 0) rc[idx] = out;
  else        tc[(size_t)(z-1)*NPIX + idx] = out;
}

// K4: per-pixel 7x7 window sums of rc^2, rc*tc, tc^2 via LDS tiles; zm; masked block reduce
#define TX 32
#define TY 8
#define PW 38
#define PH 14
#define PWP 40
__global__ __launch_bounds__(256) void k_zncc(const float* __restrict__ rc,
                                              const float* __restrict__ tc,
                                              const float* __restrict__ warped,
                                              float* __restrict__ partials) {
  __shared__ float s_rc[PH][PWP];
  __shared__ float s_t0[PH][PWP];
  __shared__ float s_t1[PH][PWP];
  __shared__ float red[8];
  int bx = blockIdx.x, by = blockIdx.y;
  int tid = threadIdx.y*TX + threadIdx.x;
  int gx0 = bx*TX - 3, gy0 = by*TY - 3;
  for (int l = tid; l < PH*PW; l += 256) {
    int ly = l / PW, lx = l - ly*PW;
    int gx = gx0 + lx, gy = gy0 + ly;
    bool in = (gx >= 0 && gx < WI && gy >= 0 && gy < HI);
    int g = gy*WI + gx;
    s_rc[ly][lx] = in ? rc[g] : 0.f;
    s_t0[ly][lx] = in ? tc[g] : 0.f;
    s_t1[ly][lx] = in ? tc[NPIX + g] : 0.f;
  }
  __syncthreads();
  int tx = threadIdx.x, ty = threadIdx.y;
  float srr = 0.f, srt0 = 0.f, stt0 = 0.f, srt1 = 0.f, stt1 = 0.f;
#pragma unroll
  for (int j = 0; j < 7; ++j)
#pragma unroll
    for (int i = 0; i < 7; ++i) {
      float r  = s_rc[ty+j][tx+i];
      float t0 = s_t0[ty+j][tx+i];
      float t1 = s_t1[ty+j][tx+i];
      srr  += r*r;
      srt0 += r*t0;  stt0 += t0*t0;
      srt1 += r*t1;  stt1 += t1*t1;
    }
  const float inv49 = 1.f/49.f;
  float v1 = srr*inv49;
  int x = bx*TX + tx, y = by*TY + ty;
  int g = y*WI + x;
  float w0v = warped[g], w1v = warped[NPIX + g];
  float zm0 = (srt0*inv49) / sqrtf(v1*(stt0*inv49) + EPSF);
  float zm1 = (srt1*inv49) / sqrtf(v1*(stt1*inv49) + EPSF);
  float sc = 0.f, cn = 0.f;
  if (w0v != 0.f) { sc += zm0; cn += 1.f; }
  if (w1v != 0.f) { sc += zm1; cn += 1.f; }
#pragma unroll
  for (int off = 32; off > 0; off >>= 1) {
    sc += __shfl_down(sc, off);
    cn += __shfl_down(cn, off);
  }
  if ((tid & 63) == 0) { red[(tid>>6)*2] = sc; red[(tid>>6)*2+1] = cn; }
  __syncthreads();
  if (tid == 0) {
    float S = red[0]+red[2]+red[4]+red[6];
    float C = red[1]+red[3]+red[5]+red[7];
    int b = by*gridDim.x + bx;
    partials[2*b]   = S;
    partials[2*b+1] = C;
  }
}

// K5: reduce partials, compute loss
__global__ __launch_bounds__(256) void k_final(const float* __restrict__ partials, int nb,
                                               float* __restrict__ out) {
  float s = 0.f, c = 0.f;
  for (int i = threadIdx.x; i < nb; i += 256) {
    s += partials[2*i];
    c += partials[2*i+1];
  }
#pragma unroll
  for (int off = 32; off > 0; off >>= 1) {
    s += __shfl_down(s, off);
    c += __shfl_down(c, off);
  }
  __shared__ float red[8];
  int tid = threadIdx.x;
  if ((tid & 63) == 0) { red[(tid>>6)*2] = s; red[(tid>>6)*2+1] = c; }
  __syncthreads();
  if (tid == 0) {
    float S = red[0]+red[2]+red[4]+red[6];
    float C = red[1]+red[3]+red[5]+red[7];
    float mean = S / fmaxf(C, 1.f);
    out[0] = (C > 0.f) ? 0.5f*(1.f - mean) : 0.f;
  }
}

extern "C" void kernel_launch(void* const* d_in, const int* in_sizes, int n_in,
                              void* d_out, int out_size, void* d_ws, size_t ws_size,
                              hipStream_t stream) {
  const float* focal  = (const float*)d_in[0];
  const float* aa     = (const float*)d_in[1];
  const float* cen    = (const float*)d_in[2];
  const float* ref    = (const float*)d_in[3];
  const float* depth  = (const float*)d_in[4];
  const float* tgts   = (const float*)d_in[5];
  float* out = (float*)d_out;

  const size_t N = NPIX;
  float* wsf      = (float*)d_ws;
  float* mats     = wsf;              // 32
  float* warped   = wsf + 32;         // 2N
  float* rc       = warped + 2*N;     // N
  float* tc       = rc + N;           // 2N
  float* tmp      = tc + 2*N;         // 3N
  float* partials = tmp + 3*N;        // 2 * 10800

  const int nb = NPIX/256;            // 10800 exact

  k_init<<<1, 64, 0, stream>>>(focal, aa, cen, mats);
  k_warp<<<nb, 256, 0, stream>>>(depth, tgts, mats, warped);
  k_rowbox<<<dim3(nb, 3), 256, 0, stream>>>(ref, warped, tmp);
  k_colbox_center<<<dim3(nb, 3), 256, 0, stream>>>(ref, warped, tmp, rc, tc);
  dim3 g4(WI/TX, HI/TY);              // 60 x 180
  k_zncc<<<g4, dim3(TX, TY), 0, stream>>>(rc, tc, warped, partials);
  k_final<<<1, 256, 0, stream>>>(partials, g4.x*g4.y, out);
}

// Round 2
// 210.464 us; speedup vs baseline: 1.2392x; 1.2392x over previous
//
#include <hip/hip_runtime.h>

#define HI 1440
#define WI 1920
#define NPIX (HI*WI)
#define EPSF 1e-8f

#define T  32   // output tile (both dims)
#define RW 44   // raw patch dim (T + 12)
#define CW 38   // centered patch dim (T + 6)
#define WHS 33  // window h-sum row stride (padded, 32+1)

// ---------------- small 3x3 helpers (K0 only) ----------------
__device__ __forceinline__ void mat3mul(const float* A, const float* B, float* C) {
#pragma unroll
  for (int i = 0; i < 3; ++i)
#pragma unroll
    for (int j = 0; j < 3; ++j)
      C[i*3+j] = A[i*3+0]*B[0+j] + A[i*3+1]*B[3+j] + A[i*3+2]*B[6+j];
}

__device__ void rodrigues_dev(const float* v, float* R) {
  float th = sqrtf(v[0]*v[0] + v[1]*v[1] + v[2]*v[2]) + 1e-12f;
  float kx = v[0]/th, ky = v[1]/th, kz = v[2]/th;
  float st = sinf(th), ct = cosf(th);
  float S[9] = {0.f,-kz,ky, kz,0.f,-kx, -ky,kx,0.f};
  float S2[9];
  mat3mul(S, S, S2);
#pragma unroll
  for (int i = 0; i < 9; ++i) R[i] = st*S[i] + (1.f-ct)*S2[i];
  R[0] += 1.f; R[4] += 1.f; R[8] += 1.f;
}

// K0: compute per-target B = K*Rt*R1^T*Kinv (3x3) and a = K*Rt*(C1-Ct) (3)
__global__ void k_init(const float* __restrict__ focal, const float* __restrict__ aa,
                       const float* __restrict__ cen, float* __restrict__ mats) {
  if (threadIdx.x != 0 || blockIdx.x != 0) return;
  float f = focal[0];
  const float u0 = WI*0.5f - 0.5f;   // 959.5
  const float v0 = HI*0.5f - 0.5f;   // 719.5
  float K[9]  = {f,0.f,u0, 0.f,f,v0, 0.f,0.f,1.f};
  float Ki[9] = {1.f/f,0.f,-u0/f, 0.f,1.f/f,-v0/f, 0.f,0.f,1.f};
  float R1[9]; rodrigues_dev(aa, R1);
  float R1T[9];
  for (int i = 0; i < 3; ++i)
    for (int j = 0; j < 3; ++j) R1T[i*3+j] = R1[j*3+i];
  for (int t = 0; t < 2; ++t) {
    float Rt[9]; rodrigues_dev(aa + 3*(t+1), Rt);
    float A[9]; mat3mul(K, Rt, A);       // A = K*Rt
    float Tm[9]; mat3mul(A, R1T, Tm);
    float B[9]; mat3mul(Tm, Ki, B);      // B = A*R1^T*Kinv
    float Cd[3] = {cen[0]-cen[3*(t+1)+0], cen[1]-cen[3*(t+1)+1], cen[2]-cen[3*(t+1)+2]};
    float a0 = A[0]*Cd[0]+A[1]*Cd[1]+A[2]*Cd[2];
    float a1 = A[3]*Cd[0]+A[4]*Cd[1]+A[5]*Cd[2];
    float a2 = A[6]*Cd[0]+A[7]*Cd[1]+A[8]*Cd[2];
    float* M = mats + t*12;
    for (int i = 0; i < 9; ++i) M[i] = B[i];
    M[9] = a0; M[10] = a1; M[11] = a2;
  }
  mats[24] = f;
}

__device__ __forceinline__ float bilerp(const float* __restrict__ img, float px, float py) {
  float x0 = floorf(px), y0 = floorf(py);
  float wx = px - x0, wy = py - y0;
  float x1 = x0 + 1.f, y1 = y0 + 1.f;
  const float xmax = (float)(WI-1), ymax = (float)(HI-1);
  bool bx0 = (x0 >= 0.f) && (x0 <= xmax);
  bool bx1 = (x1 >= 0.f) && (x1 <= xmax);
  bool by0 = (y0 >= 0.f) && (y0 <= ymax);
  bool by1 = (y1 >= 0.f) && (y1 <= ymax);
  float v00 = 0.f, v10 = 0.f, v01 = 0.f, v11 = 0.f;
  if (bx0 && by0) v00 = img[(int)y0*WI + (int)x0];
  if (bx1 && by0) v10 = img[(int)y0*WI + (int)x1];
  if (bx0 && by1) v01 = img[(int)y1*WI + (int)x0];
  if (bx1 && by1) v11 = img[(int)y1*WI + (int)x1];
  return (1.f-wy)*((1.f-wx)*v00 + wx*v10) + wy*((1.f-wx)*v01 + wx*v11);
}

// Mega-kernel: per 32x32 output tile, do warp+gather (raw 44x44), separable
// box-means -> centered maps (38x38), separable 7x7 window sums of the 5
// products -> zncc, masked accumulation -> one partial pair per block.
__global__ __launch_bounds__(256) void k_mega(const float* __restrict__ depth,
                                              const float* __restrict__ ref,
                                              const float* __restrict__ tgts,
                                              const float* __restrict__ mats,
                                              float* __restrict__ partials) {
  __shared__ float s_w[2][RW*RW];     // warped raw patches (zeros outside image)
  __shared__ float s_cen[3][CW*CW];   // centered: 0=ref, 1=t0, 2=t1
  __shared__ float s_buf[2560];       // h-sum scratch (box-mean: 44x38; window: 2 maps 38x33)
  __shared__ float s_rr[T*T];         // rr window sums
  __shared__ float s_red[8];

  const int tid = threadIdx.x;
  const int gx0 = blockIdx.x*T - 6, gy0 = blockIdx.y*T - 6;
  const float f = mats[24];

  float M0[12], M1[12];
#pragma unroll
  for (int i = 0; i < 12; ++i) { M0[i] = mats[i]; M1[i] = mats[12+i]; }

  // ---- P1: warp + gather both targets into raw patches ----
  for (int l = tid; l < RW*RW; l += 256) {
    int ry = l / RW, rx = l - ry*RW;
    int gx = gx0 + rx, gy = gy0 + ry;
    float w0v = 0.f, w1v = 0.f;
    if (gx >= 0 && gx < WI && gy >= 0 && gy < HI) {
      int g = gy*WI + gx;
      float d  = depth[g];
      float dl = (gx > 0)    ? depth[g-1]  : 0.f;
      float dr = (gx < WI-1) ? depth[g+1]  : 0.f;
      float dt = (gy > 0)    ? depth[g-WI] : 0.f;
      float db = (gy < HI-1) ? depth[g+WI] : 0.f;
      float du = 0.5f*(dr - dl);
      float dv = 0.5f*(db - dt);
      float fx = (float)gx, fy = (float)gy;
      float nx = f*du, ny = f*dv;
      float nz = (960.f - fx)*du + (720.f - fy)*dv - d;
      float nn = sqrtf(nx*nx + ny*ny + nz*nz) + EPSF;
      float wsc = 1.f/(nn*(d + EPSF));
      float px = (fx - 959.5f)/f, py = (fy - 719.5f)/f;
      float s = (nx*px + ny*py + nz)*wsc;
      {
        float w0 = M0[0]*fx + M0[1]*fy + M0[2] + M0[9]*s;
        float w1 = M0[3]*fx + M0[4]*fy + M0[5] + M0[10]*s;
        float w2 = M0[6]*fx + M0[7]*fy + M0[8] + M0[11]*s;
        w0v = bilerp(tgts, w0/(w2 + EPSF), w1/(w2 + EPSF));
      }
      {
        float w0 = M1[0]*fx + M1[1]*fy + M1[2] + M1[9]*s;
        float w1 = M1[3]*fx + M1[4]*fy + M1[5] + M1[10]*s;
        float w2 = M1[6]*fx + M1[7]*fy + M1[8] + M1[11]*s;
        w1v = bilerp(tgts + NPIX, w0/(w2 + EPSF), w1/(w2 + EPSF));
      }
    }
    s_w[0][l] = w0v;
    s_w[1][l] = w1v;
  }
  __syncthreads();

  // ---- P2/P3: per plane, separable box-mean + center ----
  for (int p = 0; p < 3; ++p) {
    // h-pass: 44 rows x 4 segments (len 10,10,10,8), running sum
    if (tid < 176) {
      int ry = tid >> 2, sg = tid & 3;
      int x0 = sg*10, len = min(10, CW - x0);
      int gy = gy0 + ry;
      const float* wp = (p > 0) ? (s_w[p-1] + ry*RW) : nullptr;
      bool rowin = (gy >= 0 && gy < HI);
      float sum = 0.f;
#pragma unroll
      for (int i = 0; i < 6; ++i) {
        int rx = x0 + i;
        float v;
        if (p == 0) { int gx = gx0 + rx; v = (rowin && gx >= 0 && gx < WI) ? ref[gy*WI+gx] : 0.f; }
        else v = wp[rx];
        sum += v;
      }
      for (int k = 0; k < len; ++k) {
        int rxa = x0 + k + 6;
        float va;
        if (p == 0) { int gx = gx0 + rxa; va = (rowin && gx >= 0 && gx < WI) ? ref[gy*WI+gx] : 0.f; }
        else va = wp[rxa];
        sum += va;
        s_buf[ry*CW + x0 + k] = sum;
        int rxs = x0 + k;
        float vs;
        if (p == 0) { int gx = gx0 + rxs; vs = (rowin && gx >= 0 && gx < WI) ? ref[gy*WI+gx] : 0.f; }
        else vs = wp[rxs];
        sum -= vs;
      }
    }
    __syncthreads();
    // v-pass + center: 38 cols x 4 segments
    if (tid < 152) {
      int cx = tid % CW, sg = tid / CW;
      int y0 = sg*10, len = min(10, CW - y0);
      float sum = 0.f;
#pragma unroll
      for (int j = 0; j < 6; ++j) sum += s_buf[(y0+j)*CW + cx];
      for (int k = 0; k < len; ++k) {
        int cy = y0 + k;
        sum += s_buf[(cy+6)*CW + cx];
        float mean = sum * (1.f/49.f);
        int gx = gx0 + cx + 3, gy = gy0 + cy + 3;
        float c = 0.f;
        if (gx >= 0 && gx < WI && gy >= 0 && gy < HI) {
          float rawc = (p == 0) ? ref[gy*WI+gx] : s_w[p-1][(cy+3)*RW + (cx+3)];
          c = rawc - mean;
        }
        s_cen[p][cy*CW + cx] = c;
        sum -= s_buf[cy*CW + cx];
      }
    }
    __syncthreads();
  }

  // ---- P4: rr window sums (separable) ----
  if (tid < 152) {                      // h: 38 rows x 4 segs of 8
    int cy = tid >> 2, sg = tid & 3;
    int x0 = sg*8;
    const float* cr = s_cen[0] + cy*CW;
    float sum = 0.f;
#pragma unroll
    for (int i = 0; i < 6; ++i) { float v = cr[x0+i]; sum += v*v; }
#pragma unroll
    for (int k = 0; k < 8; ++k) {
      float v = cr[x0+k+6]; sum += v*v;
      s_buf[cy*WHS + x0 + k] = sum;
      float u = cr[x0+k]; sum -= u*u;
    }
  }
  __syncthreads();
  if (tid < 128) {                      // v: 32 cols x 4 segs of 8
    int ox = tid & 31, sg = tid >> 5;
    int y0 = sg*8;
    float sum = 0.f;
#pragma unroll
    for (int j = 0; j < 6; ++j) sum += s_buf[(y0+j)*WHS + ox];
#pragma unroll
    for (int k = 0; k < 8; ++k) {
      int oy = y0 + k;
      sum += s_buf[(oy+6)*WHS + ox];
      s_rr[oy*T + ox] = sum;
      sum -= s_buf[oy*WHS + ox];
    }
  }
  __syncthreads();

  // ---- P5: per target: rt/tt window sums + zncc + masked accumulate ----
  float acc_s = 0.f, acc_c = 0.f;
#pragma unroll
  for (int t = 0; t < 2; ++t) {
    if (tid < 152) {                    // h: rt and tt together
      int cy = tid >> 2, sg = tid & 3;
      int x0 = sg*8;
      const float* cr = s_cen[0]   + cy*CW;
      const float* ct = s_cen[1+t] + cy*CW;
      float srt = 0.f, stt = 0.f;
#pragma unroll
      for (int i = 0; i < 6; ++i) { float r = cr[x0+i], v = ct[x0+i]; srt += r*v; stt += v*v; }
#pragma unroll
      for (int k = 0; k < 8; ++k) {
        float r = cr[x0+k+6], v = ct[x0+k+6]; srt += r*v; stt += v*v;
        s_buf[cy*WHS + x0 + k]        = srt;
        s_buf[1280 + cy*WHS + x0 + k] = stt;
        float r0 = cr[x0+k], v0 = ct[x0+k]; srt -= r0*v0; stt -= v0*v0;
      }
    }
    __syncthreads();
    if (tid < 128) {                    // v + zncc
      int ox = tid & 31, sg = tid >> 5;
      int y0 = sg*8;
      float srt = 0.f, stt = 0.f;
#pragma unroll
      for (int j = 0; j < 6; ++j) {
        srt += s_buf[(y0+j)*WHS + ox];
        stt += s_buf[1280 + (y0+j)*WHS + ox];
      }
#pragma unroll
      for (int k = 0; k < 8; ++k) {
        int oy = y0 + k;
        srt += s_buf[(oy+6)*WHS + ox];
        stt += s_buf[1280 + (oy+6)*WHS + ox];
        float wv = s_w[t][(oy+6)*RW + (ox+6)];
        if (wv != 0.f) {
          const float inv49 = 1.f/49.f;
          float rr = s_rr[oy*T + ox];
          float zm = (srt*inv49) / sqrtf((rr*inv49)*(stt*inv49) + EPSF);
          acc_s += zm; acc_c += 1.f;
        }
        srt -= s_buf[oy*WHS + ox];
        stt -= s_buf[1280 + oy*WHS + ox];
      }
    }
    __syncthreads();
  }

  // ---- P6: block reduce -> partials ----
#pragma unroll
  for (int off = 32; off > 0; off >>= 1) {
    acc_s += __shfl_down(acc_s, off);
    acc_c += __shfl_down(acc_c, off);
  }
  if ((tid & 63) == 0) { s_red[(tid>>6)*2] = acc_s; s_red[(tid>>6)*2+1] = acc_c; }
  __syncthreads();
  if (tid == 0) {
    float S = s_red[0]+s_red[2]+s_red[4]+s_red[6];
    float C = s_red[1]+s_red[3]+s_red[5]+s_red[7];
    int b = blockIdx.y*gridDim.x + blockIdx.x;
    partials[2*b]   = S;
    partials[2*b+1] = C;
  }
}

// Final: reduce partials, compute loss
__global__ __launch_bounds__(256) void k_final(const float* __restrict__ partials, int nb,
                                               float* __restrict__ out) {
  float s = 0.f, c = 0.f;
  for (int i = threadIdx.x; i < nb; i += 256) {
    s += partials[2*i];
    c += partials[2*i+1];
  }
#pragma unroll
  for (int off = 32; off > 0; off >>= 1) {
    s += __shfl_down(s, off);
    c += __shfl_down(c, off);
  }
  __shared__ float red[8];
  int tid = threadIdx.x;
  if ((tid & 63) == 0) { red[(tid>>6)*2] = s; red[(tid>>6)*2+1] = c; }
  __syncthreads();
  if (tid == 0) {
    float S = red[0]+red[2]+red[4]+red[6];
    float C = red[1]+red[3]+red[5]+red[7];
    float mean = S / fmaxf(C, 1.f);
    out[0] = (C > 0.f) ? 0.5f*(1.f - mean) : 0.f;
  }
}

extern "C" void kernel_launch(void* const* d_in, const int* in_sizes, int n_in,
                              void* d_out, int out_size, void* d_ws, size_t ws_size,
                              hipStream_t stream) {
  const float* focal  = (const float*)d_in[0];
  const float* aa     = (const float*)d_in[1];
  const float* cen    = (const float*)d_in[2];
  const float* ref    = (const float*)d_in[3];
  const float* depth  = (const float*)d_in[4];
  const float* tgts   = (const float*)d_in[5];
  float* out = (float*)d_out;

  float* wsf      = (float*)d_ws;
  float* mats     = wsf;              // 32
  float* partials = wsf + 32;         // 2 * 2700

  dim3 grid(WI/T, HI/T);              // 60 x 45 = 2700 blocks
  k_init<<<1, 64, 0, stream>>>(focal, aa, cen, mats);
  k_mega<<<grid, 256, 0, stream>>>(depth, ref, tgts, mats, partials);
  k_final<<<1, 256, 0, stream>>>(partials, grid.x*grid.y, out);
}

// Round 4
// 167.026 us; speedup vs baseline: 1.5614x; 1.2601x over previous
//
#include <hip/hip_runtime.h>

#define HI 1440
#define WI 1920
#define NPIX (HI*WI)
#define EPSF 1e-8f

#define GCOLS 52            // valid output columns per wave
#define NG 37               // ceil(1920/52)
#define SROWS 22            // output rows per strip
#define NS 66               // ceil(1440/22)
#define NWAVES (NG*NS)      // 2442
#define PROWS 35            // raw rows processed per strip (multiple of 7, >= SROWS+13-1)

typedef __fp16 h2 __attribute__((ext_vector_type(2)));

// ---------------- small 3x3 helpers (k_pre only) ----------------
__device__ __forceinline__ void mat3mul(const float* A, const float* B, float* C) {
#pragma unroll
  for (int i = 0; i < 3; ++i)
#pragma unroll
    for (int j = 0; j < 3; ++j)
      C[i*3+j] = A[i*3+0]*B[0+j] + A[i*3+1]*B[3+j] + A[i*3+2]*B[6+j];
}

__device__ void rodrigues_dev(const float* v, float* R) {
  float th = sqrtf(v[0]*v[0] + v[1]*v[1] + v[2]*v[2]) + 1e-12f;
  float kx = v[0]/th, ky = v[1]/th, kz = v[2]/th;
  float st = sinf(th), ct = cosf(th);
  float S[9] = {0.f,-kz,ky, kz,0.f,-kx, -ky,kx,0.f};
  float S2[9];
  mat3mul(S, S, S2);
#pragma unroll
  for (int i = 0; i < 9; ++i) R[i] = st*S[i] + (1.f-ct)*S2[i];
  R[0] += 1.f; R[4] += 1.f; R[8] += 1.f;
}

__global__ void k_pre(const float* __restrict__ focal, const float* __restrict__ aa,
                      const float* __restrict__ cen, float* __restrict__ mats) {
  if (threadIdx.x != 0 || blockIdx.x != 0) return;
  float f = focal[0];
  const float u0 = WI*0.5f - 0.5f;
  const float v0 = HI*0.5f - 0.5f;
  float K[9]  = {f,0.f,u0, 0.f,f,v0, 0.f,0.f,1.f};
  float Ki[9] = {1.f/f,0.f,-u0/f, 0.f,1.f/f,-v0/f, 0.f,0.f,1.f};
  float R1[9]; rodrigues_dev(aa, R1);
  float R1T[9];
  for (int i = 0; i < 3; ++i)
    for (int j = 0; j < 3; ++j) R1T[i*3+j] = R1[j*3+i];
  for (int t = 0; t < 2; ++t) {
    float Rt[9]; rodrigues_dev(aa + 3*(t+1), Rt);
    float A[9]; mat3mul(K, Rt, A);
    float Tm[9]; mat3mul(A, R1T, Tm);
    float B[9]; mat3mul(Tm, Ki, B);
    float Cd[3] = {cen[0]-cen[3*(t+1)+0], cen[1]-cen[3*(t+1)+1], cen[2]-cen[3*(t+1)+2]};
    float a0 = A[0]*Cd[0]+A[1]*Cd[1]+A[2]*Cd[2];
    float a1 = A[3]*Cd[0]+A[4]*Cd[1]+A[5]*Cd[2];
    float a2 = A[6]*Cd[0]+A[7]*Cd[1]+A[8]*Cd[2];
    float* M = mats + t*12;
    for (int i = 0; i < 9; ++i) M[i] = B[i];
    M[9] = a0; M[10] = a1; M[11] = a2;
  }
  mats[24] = f;
}

__device__ __forceinline__ float bilerp(const float* __restrict__ img, float px, float py) {
  float x0 = floorf(px), y0 = floorf(py);
  float wx = px - x0, wy = py - y0;
  float x1 = x0 + 1.f, y1 = y0 + 1.f;
  const float xmax = (float)(WI-1), ymax = (float)(HI-1);
  bool bx0 = (x0 >= 0.f) && (x0 <= xmax);
  bool bx1 = (x1 >= 0.f) && (x1 <= xmax);
  bool by0 = (y0 >= 0.f) && (y0 <= ymax);
  bool by1 = (y1 >= 0.f) && (y1 <= ymax);
  float v00 = 0.f, v10 = 0.f, v01 = 0.f, v11 = 0.f;
  if (bx0 && by0) v00 = img[(int)y0*WI + (int)x0];
  if (bx1 && by0) v10 = img[(int)y0*WI + (int)x1];
  if (bx0 && by1) v01 = img[(int)y1*WI + (int)x0];
  if (bx1 && by1) v11 = img[(int)y1*WI + (int)x1];
  return (1.f-wy)*((1.f-wx)*v00 + wx*v10) + wy*((1.f-wx)*v01 + wx*v11);
}

__device__ __forceinline__ float hsum7(float v, int ln) {
  float s = v;
  s += __shfl(v, ln-3, 64); s += __shfl(v, ln-2, 64); s += __shfl(v, ln-1, 64);
  s += __shfl(v, ln+1, 64); s += __shfl(v, ln+2, 64); s += __shfl(v, ln+3, 64);
  return s;
}

__device__ __forceinline__ h2 hsum7p(h2 v, int ln) {
  int vi = __builtin_bit_cast(int, v);
  h2 s = v;
  s += __builtin_bit_cast(h2, __shfl(vi, ln-3, 64));
  s += __builtin_bit_cast(h2, __shfl(vi, ln-2, 64));
  s += __builtin_bit_cast(h2, __shfl(vi, ln-1, 64));
  s += __builtin_bit_cast(h2, __shfl(vi, ln+1, 64));
  s += __builtin_bit_cast(h2, __shfl(vi, ln+2, 64));
  s += __builtin_bit_cast(h2, __shfl(vi, ln+3, 64));
  return s;
}

__device__ __forceinline__ float loadI(const float* __restrict__ p, int x, int y) {
  return (x >= 0 && x < WI && y >= 0 && y < HI) ? p[y*WI + x] : 0.f;
}

// Wave-streaming fused kernel: one wave = 64 raw columns (52 outputs), streams
// 35 raw rows; horizontal 7-sums via shuffles (fp16-packed pairs), vertical
// 7-sums via register rings + running sums. No LDS, no __syncthreads.
__global__ __launch_bounds__(256) void k_stream(const float* __restrict__ depth,
                                                const float* __restrict__ ref,
                                                const float* __restrict__ tgts,
                                                const float* __restrict__ mats,
                                                float* __restrict__ partials) {
  const int wid = blockIdx.x*4 + (threadIdx.x >> 6);
  if (wid >= NWAVES) return;
  const int ln = threadIdx.x & 63;
  const int g = wid % NG, st = wid / NG;
  const int R0 = st * SROWS;
  const int x = g*GCOLS - 6 + ln;
  const bool xok = (x >= 0) && (x < WI);

  const float f = mats[24];
  float M0[12], M1[12];
#pragma unroll
  for (int i = 0; i < 12; ++i) { M0[i] = mats[i]; M1[i] = mats[12+i]; }

  float dring[7], rring[7];
  h2 wring[7];
  float Hr[7], H0[7], H1[7];
  float Qrr[7], Qrt0[7], Qtt0[7], Qrt1[7], Qtt1[7];
  const h2 hz = {(__fp16)0.f, (__fp16)0.f};
#pragma unroll
  for (int k = 0; k < 7; ++k) {
    dring[k]=0.f; rring[k]=0.f; wring[k]=hz;
    Hr[k]=0.f; H0[k]=0.f; H1[k]=0.f;
    Qrr[k]=0.f; Qrt0[k]=0.f; Qtt0[k]=0.f; Qrt1[k]=0.f; Qtt1[k]=0.f;
  }
  float Sr=0.f, S0=0.f, S1=0.f;
  float Vrr=0.f, Vrt0=0.f, Vtt0=0.f, Vrt1=0.f, Vtt1=0.f;
  float acc_s=0.f, acc_c=0.f;

  // prime depth ring: rows R0-7 (slot 6) and R0-6 (slot 0)
  dring[6] = loadI(depth, x, R0-7);
  dring[0] = loadI(depth, x, R0-6);

  for (int ib = 0; ib < PROWS; ib += 7) {
#pragma unroll
    for (int j = 0; j < 7; ++j) {
      const int y = R0 - 6 + ib + j;
      dring[(j+1)%7] = loadI(depth, x, y+1);

      // ---- warp + gather at (x,y) ----
      float r = 0.f, w0 = 0.f, w1 = 0.f;
      if (xok && y >= 0 && y < HI) {
        const int gidx = y*WI + x;
        r = ref[gidx];
        float d  = dring[j];
        float dm = (x > 0)    ? depth[gidx-1] : 0.f;
        float dp = (x < WI-1) ? depth[gidx+1] : 0.f;
        float du = 0.5f*(dp - dm);
        float dv = 0.5f*(dring[(j+1)%7] - dring[(j+6)%7]);
        float fx = (float)x, fy = (float)y;
        float nx = f*du, ny = f*dv;
        float nz = (960.f - fx)*du + (720.f - fy)*dv - d;
        float nn = sqrtf(nx*nx + ny*ny + nz*nz) + EPSF;
        float wsc = 1.f/(nn*(d + EPSF));
        float px = (fx - 959.5f)/f, py = (fy - 719.5f)/f;
        float sv = (nx*px + ny*py + nz)*wsc;
        {
          float a0 = M0[0]*fx + M0[1]*fy + M0[2] + M0[9]*sv;
          float a1 = M0[3]*fx + M0[4]*fy + M0[5] + M0[10]*sv;
          float a2 = M0[6]*fx + M0[7]*fy + M0[8] + M0[11]*sv;
          float iz = 1.f/(a2 + EPSF);
          w0 = bilerp(tgts, a0*iz, a1*iz);
        }
        {
          float a0 = M1[0]*fx + M1[1]*fy + M1[2] + M1[9]*sv;
          float a1 = M1[3]*fx + M1[4]*fy + M1[5] + M1[10]*sv;
          float a2 = M1[6]*fx + M1[7]*fy + M1[8] + M1[11]*sv;
          float iz = 1.f/(a2 + EPSF);
          w1 = bilerp(tgts + NPIX, a0*iz, a1*iz);
        }
      }
      rring[j] = r;
      h2 wp = __builtin_amdgcn_cvt_pkrtz(w0, w1);
      wring[j] = wp;

      // ---- horizontal 7-sums of raw planes (all 64 lanes active) ----
      float hr = hsum7(r, ln);
      h2 hw = hsum7p(wp, ln);
      float h0 = (float)hw.x, h1 = (float)hw.y;

      // ---- vertical running box sums; box complete at yc = y-3 ----
      Sr += hr; S0 += h0; S1 += h1;
      const float Br = Sr, B0 = S0, B1 = S1;
      Sr -= Hr[(j+1)%7]; S0 -= H0[(j+1)%7]; S1 -= H1[(j+1)%7];
      Hr[j] = hr; H0[j] = h0; H1[j] = h1;

      // ---- centered values at row yc (zero outside image = zero-pad) ----
      const int yc = y - 3;
      float cr = 0.f, c0 = 0.f, c1 = 0.f;
      if (xok && yc >= 0 && yc < HI) {
        h2 wc = wring[(j+4)%7];
        cr = rring[(j+4)%7] - Br*(1.f/49.f);
        c0 = (float)wc.x - B0*(1.f/49.f);
        c1 = (float)wc.y - B1*(1.f/49.f);
      }

      // ---- product horizontal 7-sums ----
      float prr = hsum7(cr*cr, ln);
      h2 q0 = hsum7p(__builtin_amdgcn_cvt_pkrtz(cr*c0, c0*c0), ln);
      h2 q1 = hsum7p(__builtin_amdgcn_cvt_pkrtz(cr*c1, c1*c1), ln);
      float hrt0 = (float)q0.x, htt0 = (float)q0.y;
      float hrt1 = (float)q1.x, htt1 = (float)q1.y;

      // ---- vertical running window sums; window complete at yo = y-6 ----
      Vrr += prr; Vrt0 += hrt0; Vtt0 += htt0; Vrt1 += hrt1; Vtt1 += htt1;

      const int yo = y - 6;
      if (yo >= R0 && yo < R0 + SROWS && yo < HI && ln >= 6 && ln <= 57 && x < WI) {
        const int mb = __builtin_bit_cast(int, wring[(j+1)%7]);  // raw w at row yo
        const float inv49 = 1.f/49.f;
        float vr = Vrr*inv49;
        if (mb & 0xffff) {
          float zm = (Vrt0*inv49) * rsqrtf(vr*(Vtt0*inv49) + EPSF);
          acc_s += zm; acc_c += 1.f;
        }
        if (((unsigned)mb >> 16) != 0u) {
          float zm = (Vrt1*inv49) * rsqrtf(vr*(Vtt1*inv49) + EPSF);
          acc_s += zm; acc_c += 1.f;
        }
      }

      Vrr -= Qrr[(j+5)%7]; Vrt0 -= Qrt0[(j+5)%7]; Vtt0 -= Qtt0[(j+5)%7];
      Vrt1 -= Qrt1[(j+5)%7]; Vtt1 -= Qtt1[(j+5)%7];
      Qrr[(j+4)%7] = prr; Qrt0[(j+4)%7] = hrt0; Qtt0[(j+4)%7] = htt0;
      Qrt1[(j+4)%7] = hrt1; Qtt1[(j+4)%7] = htt1;
    }
  }

  // ---- wave reduce, one partial pair per wave ----
#pragma unroll
  for (int off = 32; off > 0; off >>= 1) {
    acc_s += __shfl_down(acc_s, off, 64);
    acc_c += __shfl_down(acc_c, off, 64);
  }
  if (ln == 0) { partials[2*wid] = acc_s; partials[2*wid+1] = acc_c; }
}

__global__ __launch_bounds__(256) void k_final(const float* __restrict__ partials, int nb,
                                               float* __restrict__ out) {
  float s = 0.f, c = 0.f;
  for (int i = threadIdx.x; i < nb; i += 256) {
    s += partials[2*i];
    c += partials[2*i+1];
  }
#pragma unroll
  for (int off = 32; off > 0; off >>= 1) {
    s += __shfl_down(s, off, 64);
    c += __shfl_down(c, off, 64);
  }
  __shared__ float red[8];
  int tid = threadIdx.x;
  if ((tid & 63) == 0) { red[(tid>>6)*2] = s; red[(tid>>6)*2+1] = c; }
  __syncthreads();
  if (tid == 0) {
    float S = red[0]+red[2]+red[4]+red[6];
    float C = red[1]+red[3]+red[5]+red[7];
    float mean = S / fmaxf(C, 1.f);
    out[0] = (C > 0.f) ? 0.5f*(1.f - mean) : 0.f;
  }
}

extern "C" void kernel_launch(void* const* d_in, const int* in_sizes, int n_in,
                              void* d_out, int out_size, void* d_ws, size_t ws_size,
                              hipStream_t stream) {
  const float* focal  = (const float*)d_in[0];
  const float* aa     = (const float*)d_in[1];
  const float* cen    = (const float*)d_in[2];
  const float* ref    = (const float*)d_in[3];
  const float* depth  = (const float*)d_in[4];
  const float* tgts   = (const float*)d_in[5];
  float* out = (float*)d_out;

  float* wsf      = (float*)d_ws;
  float* mats     = wsf;              // 32
  float* partials = wsf + 32;         // 2 * NWAVES

  k_pre<<<1, 64, 0, stream>>>(focal, aa, cen, mats);
  k_stream<<<(NWAVES + 3)/4, 256, 0, stream>>>(depth, ref, tgts, mats, partials);
  k_final<<<1, 256, 0, stream>>>(partials, NWAVES, out);
}